// Round 6
// baseline (374.545 us; speedup 1.0000x reference)
//
#include <hip/hip_runtime.h>

// TripleBatchTransform: roll(move) -> +noise*0.04 -> pairwise mean-pool
// (written twice) -> per-row standardize.
//
// Math: pooled p[j] = 0.5*(z[2j]+z[2j+1]), z[i] = x[(i-move)%L] + 0.04*noise[i].
// Repeated-twice signal has mean/std == mean/std over pooled values.
//
// v6: unguarded main loop. v5 (2-row pipelined, all 25 iterations wrapped in
// runtime `if (u<U)`) measured ~3.8 TB/s = ~15 GB/s/CU = 16 waves x ~1
// outstanding load: the per-iteration divergent guards stop the scheduler
// from hoisting loads -> ~1-2 in flight instead of 24. Fix: template on
// KFULL (= U/THREADS = 24 for the bench shape): 24 straight-line unguarded
// load iterations + one guarded ragged tail. p[] indices all compile-time.
// Fallback (any other shape): v5 guarded single-row kernel.
//
// History: v3 reg-resident 1-row ~119us; v4 split kernels REGRESSED (~147us,
// cross-kernel L3 reuse too far); v5 2-row pipeline ~106us; floor 64.5us.

#define THREADS 1024
#define NWAVES (THREADS / 64)
#define KMAX 25

typedef float f32x4 __attribute__((ext_vector_type(4)));

__device__ __forceinline__ void row_stats(
    float sum, float sq, int tid, int J,
    float* s_sum, float* s_sq, float* s_mu, float* s_isd,
    float& mu, float& isd)
{
    #pragma unroll
    for (int off = 32; off > 0; off >>= 1) {
        sum += __shfl_down(sum, off, 64);
        sq  += __shfl_down(sq,  off, 64);
    }
    const int wave = tid >> 6;
    if ((tid & 63) == 0) { s_sum[wave] = sum; s_sq[wave] = sq; }
    __syncthreads();
    if (tid == 0) {
        float ts = 0.f, tq = 0.f;
        #pragma unroll
        for (int w = 0; w < NWAVES; ++w) { ts += s_sum[w]; tq += s_sq[w]; }
        float invJ = 1.0f / (float)J;
        float m   = ts * invJ;
        float var = tq * invJ - m * m;
        *s_mu  = m;
        *s_isd = rsqrtf(fmaxf(var, 1e-30f));
    }
    __syncthreads();
    mu  = *s_mu;
    isd = *s_isd;
}

// generic (non-fast4) one-row path: two-pass recompute
__device__ __forceinline__ void generic_row(
    const float* __restrict__ xrow, const float* __restrict__ noise,
    float* __restrict__ orow, int L, int mv, int tid,
    float* s_sum, float* s_sq, float* s_mu, float* s_isd)
{
    const int J = L >> 1;
    const bool fast2 = ((mv & 1) == 0) && ((L & 1) == 0);
    float sum = 0.f, sq = 0.f;
    for (int j = tid; j < J; j += THREADS) {
        int s = 2 * j - mv; if (s < 0) s += L;
        float a, c;
        if (fast2) { float2 v = *(const float2*)(xrow + s); a = v.x; c = v.y; }
        else { int s1 = s + 1; if (s1 >= L) s1 -= L; a = xrow[s]; c = xrow[s1]; }
        float2 nv = *(const float2*)(noise + 2 * j);
        float p = 0.5f * (a + c + 0.04f * (nv.x + nv.y));
        sum += p; sq += p * p;
    }
    float mu, isd;
    row_stats(sum, sq, tid, J, s_sum, s_sq, s_mu, s_isd, mu, isd);
    for (int j = tid; j < J; j += THREADS) {
        int s = 2 * j - mv; if (s < 0) s += L;
        float a, c;
        if (fast2) { float2 v = *(const float2*)(xrow + s); a = v.x; c = v.y; }
        else { int s1 = s + 1; if (s1 >= L) s1 -= L; a = xrow[s]; c = xrow[s1]; }
        float2 nv = *(const float2*)(noise + 2 * j);
        float p = 0.5f * (a + c + 0.04f * (nv.x + nv.y));
        float r = (p - mu) * isd;
        *(float2*)(orow + 2 * j) = make_float2(r, r);
    }
}

// Two-row pipelined kernel, KFULL unguarded iterations + 1 guarded tail.
template<int KFULL>
__global__ __launch_bounds__(THREADS) void tbt_pipe(
    const float* __restrict__ x,
    const float* __restrict__ noise,
    const int* __restrict__ movep,
    float* __restrict__ out,
    int L)
{
    const int tid = threadIdx.x;
    const int J = L >> 1;
    const int U = J >> 1;

    int mv = movep[0];
    mv %= L; if (mv < 0) mv += L;

    const size_t roff = (size_t)(2 * blockIdx.x) * (size_t)L;
    const float* __restrict__ xr0 = x + roff;
    const float* __restrict__ xr1 = xr0 + L;
    float* __restrict__ or0 = out + roff;
    float* __restrict__ or1 = or0 + L;

    __shared__ float s_sum[NWAVES], s_sq[NWAVES];
    __shared__ float s_stat[4];

    const bool fast4 = ((mv & 3) == 0) && ((L & 3) == 0);
    if (!fast4) {
        generic_row(xr0, noise, or0, L, mv, tid, s_sum, s_sq, &s_stat[0], &s_stat[1]);
        __syncthreads();
        generic_row(xr1, noise, or1, L, mv, tid, s_sum, s_sq, &s_stat[2], &s_stat[3]);
        return;
    }

    float p0[2 * (KFULL + 1)], p1[2 * (KFULL + 1)];
    float sum = 0.f, sq = 0.f;

    // ---- Phase A: load row0 -> p0 (KFULL unguarded + tail) ----
    #pragma unroll
    for (int k = 0; k < KFULL; ++k) {
        const int u = tid + k * THREADS;
        int s = 4 * u - mv; if (s < 0) s += L;
        f32x4 v = __builtin_nontemporal_load((const f32x4*)(xr0 + s));
        float4 n = *(const float4*)(noise + 4 * u);
        float a = 0.5f * (v.x + v.y) + 0.02f * (n.x + n.y);
        float c = 0.5f * (v.z + v.w) + 0.02f * (n.z + n.w);
        p0[2 * k]     = a;
        p0[2 * k + 1] = c;
        sum += a + c;
        sq  += a * a + c * c;
    }
    {
        const int u = tid + KFULL * THREADS;
        if (u < U) {
            int s = 4 * u - mv; if (s < 0) s += L;
            f32x4 v = __builtin_nontemporal_load((const f32x4*)(xr0 + s));
            float4 n = *(const float4*)(noise + 4 * u);
            float a = 0.5f * (v.x + v.y) + 0.02f * (n.x + n.y);
            float c = 0.5f * (v.z + v.w) + 0.02f * (n.z + n.w);
            p0[2 * KFULL]     = a;
            p0[2 * KFULL + 1] = c;
            sum += a + c;
            sq  += a * a + c * c;
        }
    }
    float mu0, isd0;
    row_stats(sum, sq, tid, J, s_sum, s_sq, &s_stat[0], &s_stat[1], mu0, isd0);

    // ---- Phase B: load row1 -> p1 while storing row0 normalized ----
    sum = 0.f; sq = 0.f;
    #pragma unroll
    for (int k = 0; k < KFULL; ++k) {
        const int u = tid + k * THREADS;
        int s = 4 * u - mv; if (s < 0) s += L;
        f32x4 v = __builtin_nontemporal_load((const f32x4*)(xr1 + s));
        float4 n = *(const float4*)(noise + 4 * u);
        float ra = (p0[2 * k]     - mu0) * isd0;
        float rc = (p0[2 * k + 1] - mu0) * isd0;
        f32x4 o = {ra, ra, rc, rc};
        __builtin_nontemporal_store(o, (f32x4*)(or0 + 4 * u));
        float a = 0.5f * (v.x + v.y) + 0.02f * (n.x + n.y);
        float c = 0.5f * (v.z + v.w) + 0.02f * (n.z + n.w);
        p1[2 * k]     = a;
        p1[2 * k + 1] = c;
        sum += a + c;
        sq  += a * a + c * c;
    }
    {
        const int u = tid + KFULL * THREADS;
        if (u < U) {
            int s = 4 * u - mv; if (s < 0) s += L;
            f32x4 v = __builtin_nontemporal_load((const f32x4*)(xr1 + s));
            float4 n = *(const float4*)(noise + 4 * u);
            float ra = (p0[2 * KFULL]     - mu0) * isd0;
            float rc = (p0[2 * KFULL + 1] - mu0) * isd0;
            f32x4 o = {ra, ra, rc, rc};
            __builtin_nontemporal_store(o, (f32x4*)(or0 + 4 * u));
            float a = 0.5f * (v.x + v.y) + 0.02f * (n.x + n.y);
            float c = 0.5f * (v.z + v.w) + 0.02f * (n.z + n.w);
            p1[2 * KFULL]     = a;
            p1[2 * KFULL + 1] = c;
            sum += a + c;
            sq  += a * a + c * c;
        }
    }
    float mu1, isd1;
    row_stats(sum, sq, tid, J, s_sum, s_sq, &s_stat[2], &s_stat[3], mu1, isd1);

    // ---- Phase C: store row1 from registers ----
    #pragma unroll
    for (int k = 0; k < KFULL; ++k) {
        const int u = tid + k * THREADS;
        float ra = (p1[2 * k]     - mu1) * isd1;
        float rc = (p1[2 * k + 1] - mu1) * isd1;
        f32x4 o = {ra, ra, rc, rc};
        __builtin_nontemporal_store(o, (f32x4*)(or1 + 4 * u));
    }
    {
        const int u = tid + KFULL * THREADS;
        if (u < U) {
            float ra = (p1[2 * KFULL]     - mu1) * isd1;
            float rc = (p1[2 * KFULL + 1] - mu1) * isd1;
            f32x4 o = {ra, ra, rc, rc};
            __builtin_nontemporal_store(o, (f32x4*)(or1 + 4 * u));
        }
    }
}

// ---------------- fallback: guarded single-row kernel (any shape) ----------------

__global__ __launch_bounds__(THREADS) void tbt_kernel(
    const float* __restrict__ x,
    const float* __restrict__ noise,
    const int* __restrict__ movep,
    float* __restrict__ out,
    int L)
{
    const int b   = blockIdx.x;
    const int tid = threadIdx.x;
    const int J   = L >> 1;

    int mv = movep[0];
    mv %= L; if (mv < 0) mv += L;

    const float* __restrict__ xrow = x + (size_t)b * (size_t)L;
    float* __restrict__ orow       = out + (size_t)b * (size_t)L;

    const bool fast4 = ((mv & 3) == 0) && ((L & 3) == 0);

    const int U  = J >> 1;
    const int nk = (U + THREADS - 1) / THREADS;

    __shared__ float s_sum[NWAVES], s_sq[NWAVES];
    __shared__ float s_stat[2];

    if (fast4 && nk <= KMAX) {
        float p[2 * KMAX];
        float sum = 0.f, sq = 0.f;

        #pragma unroll
        for (int k = 0; k < KMAX; ++k) {
            const int u = tid + k * THREADS;
            if (u < U) {
                int s = 4 * u - mv; if (s < 0) s += L;
                f32x4 v = __builtin_nontemporal_load((const f32x4*)(xrow + s));
                float4 n = *(const float4*)(noise + 4 * u);
                float a = 0.5f * (v.x + v.y) + 0.02f * (n.x + n.y);
                float c = 0.5f * (v.z + v.w) + 0.02f * (n.z + n.w);
                p[2 * k]     = a;
                p[2 * k + 1] = c;
                sum += a + c;
                sq  += a * a + c * c;
            }
        }

        float mu, isd;
        row_stats(sum, sq, tid, J, s_sum, s_sq, &s_stat[0], &s_stat[1], mu, isd);

        #pragma unroll
        for (int k = 0; k < KMAX; ++k) {
            const int u = tid + k * THREADS;
            if (u < U) {
                float ra = (p[2 * k]     - mu) * isd;
                float rc = (p[2 * k + 1] - mu) * isd;
                f32x4 o = {ra, ra, rc, rc};
                __builtin_nontemporal_store(o, (f32x4*)(orow + 4 * u));
            }
        }
        return;
    }

    generic_row(xrow, noise, orow, L, mv, tid, s_sum, s_sq, &s_stat[0], &s_stat[1]);
}

extern "C" void kernel_launch(void* const* d_in, const int* in_sizes, int n_in,
                              void* d_out, int out_size, void* d_ws, size_t ws_size,
                              hipStream_t stream) {
    const float* x     = (const float*)d_in[0];
    const float* noise = (const float*)d_in[1];
    const int*   move  = (const int*)d_in[2];
    float*       out   = (float*)d_out;

    const int L = in_sizes[1];             // 100000
    const int B = in_sizes[0] / L;         // 512

    const int J  = L >> 1;
    const int U  = J >> 1;                 // 25000 for the bench
    const int KF = U / THREADS;            // 24 for the bench

    // Unguarded-unroll pipeline for the bench shape; guarded fallback else.
    if (((L & 3) == 0) && ((B & 1) == 0) && B >= 2 && KF == 24 && U <= 25 * THREADS) {
        tbt_pipe<24><<<B / 2, THREADS, 0, stream>>>(x, noise, move, out, L);
    } else {
        tbt_kernel<<<B, THREADS, 0, stream>>>(x, noise, move, out, L);
    }
}

// Round 7
// 348.584 us; speedup vs baseline: 1.0745x; 1.0745x over previous
//
#include <hip/hip_runtime.h>

// TripleBatchTransform: roll(move) -> +noise*0.04 -> pairwise mean-pool
// (written twice) -> per-row standardize.
//
// Math: pooled p[j] = 0.5*(z[2j]+z[2j+1]), z[i] = x[(i-move)%L] + 0.04*noise[i].
// Repeated-twice signal has mean/std == mean/std over pooled values.
//
// v7: unguarded loads + ONE row per block (register-budget fix).
// Ledger: v3 guarded 1-row regs ~119us; v4 split kernels ~147us (REGRESS);
// v5 guarded 2-row pipeline ~106us; v6 unguarded 2-row ~131us (REGRESS:
// 100 live p-floats > 128-VGPR cap -> allocator picked VGPR=64 and spilled,
// WRITE_SIZE 333MB vs 201 ideal). Fix: 1 row = 50 p-floats fits; keep the
// 24 straight-line unguarded load iterations (MLP depth), and pin the
// register budget with __launch_bounds__(1024, 4) -> 128 VGPR cap so the
// allocator doesn't chase 2-block occupancy (LDS/structure gives 1 block/CU
// anyway). nt-loads for x (single use), nt-stores for out.
// Floor: 406MB @ 6.3TB/s = 64.5us.

#define THREADS 1024
#define NWAVES (THREADS / 64)
#define KMAX 25

typedef float f32x4 __attribute__((ext_vector_type(4)));

__device__ __forceinline__ void row_stats(
    float sum, float sq, int tid, int J,
    float* s_sum, float* s_sq, float* s_mu, float* s_isd,
    float& mu, float& isd)
{
    #pragma unroll
    for (int off = 32; off > 0; off >>= 1) {
        sum += __shfl_down(sum, off, 64);
        sq  += __shfl_down(sq,  off, 64);
    }
    const int wave = tid >> 6;
    if ((tid & 63) == 0) { s_sum[wave] = sum; s_sq[wave] = sq; }
    __syncthreads();
    if (tid == 0) {
        float ts = 0.f, tq = 0.f;
        #pragma unroll
        for (int w = 0; w < NWAVES; ++w) { ts += s_sum[w]; tq += s_sq[w]; }
        float invJ = 1.0f / (float)J;
        float m   = ts * invJ;
        float var = tq * invJ - m * m;
        *s_mu  = m;
        *s_isd = rsqrtf(fmaxf(var, 1e-30f));
    }
    __syncthreads();
    mu  = *s_mu;
    isd = *s_isd;
}

// generic (non-fast4) one-row path: two-pass recompute
__device__ __forceinline__ void generic_row(
    const float* __restrict__ xrow, const float* __restrict__ noise,
    float* __restrict__ orow, int L, int mv, int tid,
    float* s_sum, float* s_sq, float* s_mu, float* s_isd)
{
    const int J = L >> 1;
    const bool fast2 = ((mv & 1) == 0) && ((L & 1) == 0);
    float sum = 0.f, sq = 0.f;
    for (int j = tid; j < J; j += THREADS) {
        int s = 2 * j - mv; if (s < 0) s += L;
        float a, c;
        if (fast2) { float2 v = *(const float2*)(xrow + s); a = v.x; c = v.y; }
        else { int s1 = s + 1; if (s1 >= L) s1 -= L; a = xrow[s]; c = xrow[s1]; }
        float2 nv = *(const float2*)(noise + 2 * j);
        float p = 0.5f * (a + c + 0.04f * (nv.x + nv.y));
        sum += p; sq += p * p;
    }
    float mu, isd;
    row_stats(sum, sq, tid, J, s_sum, s_sq, s_mu, s_isd, mu, isd);
    for (int j = tid; j < J; j += THREADS) {
        int s = 2 * j - mv; if (s < 0) s += L;
        float a, c;
        if (fast2) { float2 v = *(const float2*)(xrow + s); a = v.x; c = v.y; }
        else { int s1 = s + 1; if (s1 >= L) s1 -= L; a = xrow[s]; c = xrow[s1]; }
        float2 nv = *(const float2*)(noise + 2 * j);
        float p = 0.5f * (a + c + 0.04f * (nv.x + nv.y));
        float r = (p - mu) * isd;
        *(float2*)(orow + 2 * j) = make_float2(r, r);
    }
}

// One row per block, KFULL unguarded load iterations + 1 guarded tail.
// __launch_bounds__(1024, 4): 4 waves/EU min -> 128-VGPR cap; 50 p-floats
// + pipeline temps fit without spilling (v6 lesson).
template<int KFULL>
__global__ __launch_bounds__(THREADS, 4) void tbt_row(
    const float* __restrict__ x,
    const float* __restrict__ noise,
    const int* __restrict__ movep,
    float* __restrict__ out,
    int L)
{
    const int tid = threadIdx.x;
    const int J = L >> 1;
    const int U = J >> 1;

    int mv = movep[0];
    mv %= L; if (mv < 0) mv += L;

    const size_t roff = (size_t)blockIdx.x * (size_t)L;
    const float* __restrict__ xrow = x + roff;
    float* __restrict__ orow       = out + roff;

    __shared__ float s_sum[NWAVES], s_sq[NWAVES];
    __shared__ float s_stat[2];

    const bool fast4 = ((mv & 3) == 0) && ((L & 3) == 0);
    if (!fast4) {
        generic_row(xrow, noise, orow, L, mv, tid, s_sum, s_sq, &s_stat[0], &s_stat[1]);
        return;
    }

    float p[2 * (KFULL + 1)];
    float sum = 0.f, sq = 0.f;

    // ---- Phase A: load row -> p (KFULL straight-line + guarded tail) ----
    #pragma unroll
    for (int k = 0; k < KFULL; ++k) {
        const int u = tid + k * THREADS;
        int s = 4 * u - mv; if (s < 0) s += L;
        f32x4 v = __builtin_nontemporal_load((const f32x4*)(xrow + s));
        float4 n = *(const float4*)(noise + 4 * u);
        float a = 0.5f * (v.x + v.y) + 0.02f * (n.x + n.y);
        float c = 0.5f * (v.z + v.w) + 0.02f * (n.z + n.w);
        p[2 * k]     = a;
        p[2 * k + 1] = c;
        sum += a + c;
        sq  += a * a + c * c;
    }
    {
        const int u = tid + KFULL * THREADS;
        if (u < U) {
            int s = 4 * u - mv; if (s < 0) s += L;
            f32x4 v = __builtin_nontemporal_load((const f32x4*)(xrow + s));
            float4 n = *(const float4*)(noise + 4 * u);
            float a = 0.5f * (v.x + v.y) + 0.02f * (n.x + n.y);
            float c = 0.5f * (v.z + v.w) + 0.02f * (n.z + n.w);
            p[2 * KFULL]     = a;
            p[2 * KFULL + 1] = c;
            sum += a + c;
            sq  += a * a + c * c;
        }
    }

    float mu, isd;
    row_stats(sum, sq, tid, J, s_sum, s_sq, &s_stat[0], &s_stat[1], mu, isd);

    // ---- Phase B: pure nt-store stream from registers ----
    #pragma unroll
    for (int k = 0; k < KFULL; ++k) {
        const int u = tid + k * THREADS;
        float ra = (p[2 * k]     - mu) * isd;
        float rc = (p[2 * k + 1] - mu) * isd;
        f32x4 o = {ra, ra, rc, rc};
        __builtin_nontemporal_store(o, (f32x4*)(orow + 4 * u));
    }
    {
        const int u = tid + KFULL * THREADS;
        if (u < U) {
            float ra = (p[2 * KFULL]     - mu) * isd;
            float rc = (p[2 * KFULL + 1] - mu) * isd;
            f32x4 o = {ra, ra, rc, rc};
            __builtin_nontemporal_store(o, (f32x4*)(orow + 4 * u));
        }
    }
}

// ---------------- fallback: guarded single-row kernel (any shape) ----------------

__global__ __launch_bounds__(THREADS) void tbt_kernel(
    const float* __restrict__ x,
    const float* __restrict__ noise,
    const int* __restrict__ movep,
    float* __restrict__ out,
    int L)
{
    const int b   = blockIdx.x;
    const int tid = threadIdx.x;
    const int J   = L >> 1;

    int mv = movep[0];
    mv %= L; if (mv < 0) mv += L;

    const float* __restrict__ xrow = x + (size_t)b * (size_t)L;
    float* __restrict__ orow       = out + (size_t)b * (size_t)L;

    const bool fast4 = ((mv & 3) == 0) && ((L & 3) == 0);

    const int U  = J >> 1;
    const int nk = (U + THREADS - 1) / THREADS;

    __shared__ float s_sum[NWAVES], s_sq[NWAVES];
    __shared__ float s_stat[2];

    if (fast4 && nk <= KMAX) {
        float p[2 * KMAX];
        float sum = 0.f, sq = 0.f;

        #pragma unroll
        for (int k = 0; k < KMAX; ++k) {
            const int u = tid + k * THREADS;
            if (u < U) {
                int s = 4 * u - mv; if (s < 0) s += L;
                f32x4 v = __builtin_nontemporal_load((const f32x4*)(xrow + s));
                float4 n = *(const float4*)(noise + 4 * u);
                float a = 0.5f * (v.x + v.y) + 0.02f * (n.x + n.y);
                float c = 0.5f * (v.z + v.w) + 0.02f * (n.z + n.w);
                p[2 * k]     = a;
                p[2 * k + 1] = c;
                sum += a + c;
                sq  += a * a + c * c;
            }
        }

        float mu, isd;
        row_stats(sum, sq, tid, J, s_sum, s_sq, &s_stat[0], &s_stat[1], mu, isd);

        #pragma unroll
        for (int k = 0; k < KMAX; ++k) {
            const int u = tid + k * THREADS;
            if (u < U) {
                float ra = (p[2 * k]     - mu) * isd;
                float rc = (p[2 * k + 1] - mu) * isd;
                f32x4 o = {ra, ra, rc, rc};
                __builtin_nontemporal_store(o, (f32x4*)(orow + 4 * u));
            }
        }
        return;
    }

    generic_row(xrow, noise, orow, L, mv, tid, s_sum, s_sq, &s_stat[0], &s_stat[1]);
}

extern "C" void kernel_launch(void* const* d_in, const int* in_sizes, int n_in,
                              void* d_out, int out_size, void* d_ws, size_t ws_size,
                              hipStream_t stream) {
    const float* x     = (const float*)d_in[0];
    const float* noise = (const float*)d_in[1];
    const int*   move  = (const int*)d_in[2];
    float*       out   = (float*)d_out;

    const int L = in_sizes[1];             // 100000
    const int B = in_sizes[0] / L;         // 512

    const int J  = L >> 1;
    const int U  = J >> 1;                 // 25000 for the bench
    const int KF = U / THREADS;            // 24 for the bench

    // Unguarded-unroll 1-row kernel for the bench shape; guarded fallback else.
    if (((L & 3) == 0) && KF == 24 && U <= 25 * THREADS) {
        tbt_row<24><<<B, THREADS, 0, stream>>>(x, noise, move, out, L);
    } else {
        tbt_kernel<<<B, THREADS, 0, stream>>>(x, noise, move, out, L);
    }
}